// Round 4
// baseline (187.000 us; speedup 1.0000x reference)
//
#include <hip/hip_runtime.h>
#include <hip/hip_fp16.h>

#define Bsz 1024
#define Mm  2048
#define Rr  8192
#define EMAX 32   // ushort slots per E column (col nnz mean ~4.1)
#define SMAX 64   // ushort slots per S row    (row nnz mean ~16.4)

typedef unsigned short ushort_t;

// ---- pass 0: prefill slist pads (0x4000 -> s=0) + zero ecnt/scnt. 300 KB. ----
__global__ __launch_bounds__(256) void zero_fill(
    unsigned* __restrict__ slist_u, int* __restrict__ ecnt, int* __restrict__ scnt)
{
    const int tid = blockIdx.x * 256 + threadIdx.x;      // grid 296 -> 75776
    if (tid < 65536)       slist_u[tid] = 0x40004000u;   // slist: Mm*SMAX ushorts
    else if (tid < 73728)  ecnt[tid - 65536] = 0;        // Rr ints
    else                   scnt[tid - 73728] = 0;        // Mm ints
}

// ---- pass 1: blocks 0..511 transpose+log; 512..2559 copy-style E|S scan.
// R1-R3 falsified per-thread MLP as prep's limiter (3 load engines, same 53us).
// New variable: STREAM TOPOLOGY. Old: ~1-2K private 32KB row streams scattered
// over 128MB (DRAM page thrash, FETCH at 1.45 TB/s). New: copy-kernel traversal
// - grid-stride int4 sweep, the GPU's in-flight window is one contiguous ~8MB
// span sliding forward (m13's 6.3 TB/s pattern), 0 LDS / 0 barriers on the scan
// path -> full 32 waves/CU TLP. Compaction via rare global atomics (order in
// elist/slist is irrelevant - both are summed downstream).
__global__ __launch_bounds__(256) void prep_kernel(
    const float* __restrict__ conc, const int* __restrict__ E, const int* __restrict__ S,
    __half2* __restrict__ logcTh2, int* __restrict__ ecnt, ushort_t* __restrict__ elist,
    int* __restrict__ scnt, ushort_t* __restrict__ slist)
{
    __shared__ float tile[64][65];               // transpose role only (16.6 KB)
    const int bid = blockIdx.x;
    const int t   = threadIdx.x;

    if (bid < 512) {                             // ---- transpose + log -> fp16 ----
        const int mt = (bid & 31) * 64;          // Mm/64 = 32
        const int bt = (bid >> 5) * 64;
        const int lm = t & 63;
        const int w  = t >> 6;
        for (int i = w; i < 64; i += 4)
            tile[lm][i] = __logf(conc[(size_t)(bt + i) * Mm + mt + lm]);
        __syncthreads();
        const int s       = bt >> 7;             // b-slice (128 b)
        const int colbase = (bt & 127) >> 1;
        __half2* dst = logcTh2 + (size_t)s * (Mm * 64);
        for (int idx = t; idx < 64 * 32; idx += 256) {
            const int j = idx >> 5, bp = idx & 31;
            dst[(mt + j) * 64 + colbase + bp] =
                __floats2half2_rn(tile[j][2 * bp], tile[j][2 * bp + 1]);
        }
    } else {                                     // ---- copy-style scan ----
        const int gl = (bid - 512) * 256 + t;    // 0..524287 lanes
        // E sweep: 8 x 8MB sliding windows (4194304 int4 total)
        const int4* E4 = (const int4*)E;
        #pragma unroll
        for (int i = 0; i < 8; ++i) {
            const unsigned idx4 = i * 524288u + gl;
            const int4 v = E4[idx4];
            if (v.x | v.y | v.z | v.w) {         // rare (~0.8% of int4)
                const int ib = (int)(idx4 << 2); // int index
                const int m = ib >> 13, r0 = ib & 8191;
                int vv[4] = {v.x, v.y, v.z, v.w};
                #pragma unroll
                for (int q = 0; q < 4; ++q)
                    if (vv[q]) {
                        int slot = atomicAdd(&ecnt[r0 + q], 1);
                        if (slot < EMAX)
                            elist[(r0 + q) * EMAX + slot] = (ushort_t)((vv[q] << 11) | m);
                    }
            }
        }
        // S sweep
        const int4* S4 = (const int4*)S;
        #pragma unroll
        for (int i = 0; i < 8; ++i) {
            const unsigned idx4 = i * 524288u + gl;
            const int4 v = S4[idx4];
            if (v.x | v.y | v.z | v.w) {
                const int ib = (int)(idx4 << 2);
                const int m = ib >> 13, r0 = ib & 8191;
                int vv[4] = {v.x, v.y, v.z, v.w};
                #pragma unroll
                for (int q = 0; q < 4; ++q)
                    if (vv[q]) {
                        int slot = atomicAdd(&scnt[m], 1);
                        if (slot < SMAX)
                            slist[m * SMAX + slot] = (ushort_t)(((vv[q] + 2) << 13) | (r0 + q));
                    }
            }
        }
    }
}

// ---- pass 2: VTh[s][r][64] = k[r]*exp(sum e*logcTh[s][m][64]) ----
// Batched: all 8 rows' scalar loads first (one latency hop), then 32+ gathers.
// Pad entries are garbage (elist not zeroed) -> weights validity-masked; addr &0x7FF in-bounds.
__global__ __launch_bounds__(256) void rates_kernel(
    const __half2* __restrict__ logcTh2, const float* __restrict__ kvec,
    const int* __restrict__ ecnt, const ushort_t* __restrict__ elist,
    __half2* __restrict__ VTh)
{
    const int s   = blockIdx.x & 7;              // XCD pin: logc slice 512 KB L2-hot
    const int rch = blockIdx.x >> 3;             // 0..255, 32 r each
    const int col = threadIdx.x & 63;
    const int wr  = __builtin_amdgcn_readfirstlane(threadIdx.x >> 6);
    const __half2* lc = logcTh2 + (size_t)s * (Mm * 64);
    __half2* vt = VTh + (size_t)s * (Rr * 64);
    const int rb = rch * 32 + wr * 8;

    int  cnt[8]; int2 L0[8]; float kk[8];        // batch phase: independent s_loads
    #pragma unroll
    for (int i = 0; i < 8; ++i) {
        const int r = rb + i;
        cnt[i] = min(ecnt[r], EMAX);             // clamp: atomic counts can exceed slots
        L0[i]  = *(const int2*)(elist + (r << 5));
        kk[i]  = kvec[r];
    }
    float2 acc[8];
    unsigned w; float2 g; float v0, v1;
    #define EG2(word, c0, c1, A)                                               \
        w = (unsigned)(word);                                                  \
        v0 = (c0) ? (float)((w & 0xFFFF) >> 11) : 0.f;                         \
        v1 = (c1) ? (float)(w >> 27) : 0.f;                                    \
        g = __half22float2(lc[(w & 0x7FF) * 64 + col]);                        \
        A.x += v0 * g.x;  A.y += v0 * g.y;                                     \
        g = __half22float2(lc[((w >> 16) & 0x7FF) * 64 + col]);                \
        A.x += v1 * g.x;  A.y += v1 * g.y;
    #pragma unroll
    for (int i = 0; i < 8; ++i) {                // 32 gathers, one dependency level
        acc[i] = make_float2(0.f, 0.f);
        EG2(L0[i].x, cnt[i] > 0, cnt[i] > 1, acc[i])
        EG2(L0[i].y, cnt[i] > 2, cnt[i] > 3, acc[i])
    }
    #pragma unroll
    for (int i = 0; i < 8; ++i) {                // rare wave-uniform tails
        for (int j = 4; j < cnt[i]; j += 4) {
            int2 T = *(const int2*)(elist + ((rb + i) << 5) + j);
            EG2(T.x, j + 0 < cnt[i], j + 1 < cnt[i], acc[i])
            EG2(T.y, j + 2 < cnt[i], j + 3 < cnt[i], acc[i])
        }
    }
    #undef EG2
    #pragma unroll
    for (int i = 0; i < 8; ++i)
        vt[(rb + i) * 64 + col] =
            __floats2half2_rn(kk[i] * __expf(acc[i].x), kk[i] * __expf(acc[i].y));
}

// ---- pass 3: out[b][m] = sum s*VTh[s][r][64]; batched lists; LDS transpose stores ----
__global__ __launch_bounds__(256) void assemble_kernel(
    const __half2* __restrict__ VTh, const int* __restrict__ scnt,
    const ushort_t* __restrict__ slist, float* __restrict__ out)
{
    __shared__ float tile[128][17];              // [b-local][m-local] 8.5 KB
    const int s   = blockIdx.x & 7;              // same XCD pin as rates
    const int mch = blockIdx.x >> 3;             // 0..127, 16 m each
    const int col = threadIdx.x & 63;
    const int wm  = __builtin_amdgcn_readfirstlane(threadIdx.x >> 6);
    const __half2* vt = VTh + (size_t)s * (Rr * 64);
    const int m0 = mch * 16;

    int scn[4]; int4 W0[4], W1[4];               // batch phase: independent s_loads
    #pragma unroll
    for (int i = 0; i < 4; ++i) {
        const int m = m0 + i * 4 + wm;
        scn[i] = min(scnt[m], SMAX);             // clamp: atomic counts can exceed slots
        W0[i]  = *(const int4*)(slist + (m << 6));
        W1[i]  = *(const int4*)(slist + (m << 6) + 8);
    }
    unsigned w; float2 v; float sw;
    #define SG(word, A)                                                        \
        w = (unsigned)(word);                                                  \
        v = __half22float2(vt[(w & 0x1FFF) * 64 + col]);                       \
        sw = (float)((int)((w & 0xFFFF) >> 13) - 2);                           \
        A.x += sw * v.x;  A.y += sw * v.y;                                     \
        v = __half22float2(vt[((w >> 16) & 0x1FFF) * 64 + col]);               \
        sw = (float)((int)(w >> 29) - 2);                                      \
        A.x += sw * v.x;  A.y += sw * v.y;
    #pragma unroll
    for (int i = 0; i < 4; ++i) {
        const int ml = i * 4 + wm;
        float2 a = make_float2(0.f, 0.f);
        SG(W0[i].x, a) SG(W0[i].y, a) SG(W0[i].z, a) SG(W0[i].w, a)
        SG(W1[i].x, a) SG(W1[i].y, a) SG(W1[i].z, a) SG(W1[i].w, a)
        for (int j = 16; j < scn[i]; j += 8) {   // pads materialized -> safe groups
            int4 T = *(const int4*)(slist + ((m0 + ml) << 6) + j);
            SG(T.x, a) SG(T.y, a) SG(T.z, a) SG(T.w, a)
        }
        tile[2 * col][ml]     = a.x;
        tile[2 * col + 1][ml] = a.y;
    }
    #undef SG
    __syncthreads();
    #pragma unroll
    for (int pass = 0; pass < 2; ++pass) {
        const int bl = (threadIdx.x >> 2) + pass * 64;
        const int fl = threadIdx.x & 3;
        float4 vv = *(const float4*)&tile[bl][fl * 4];
        *(float4*)(out + (size_t)(s * 128 + bl) * Mm + m0 + fl * 4) = vv;
    }
}

extern "C" void kernel_launch(void* const* d_in, const int* in_sizes, int n_in,
                              void* d_out, int out_size, void* d_ws, size_t ws_size,
                              hipStream_t stream) {
    const float* conc = (const float*)d_in[0];
    const int*   E    = (const int*)d_in[1];
    const int*   S    = (const int*)d_in[2];
    const float* kvec = (const float*)d_in[3];
    float* out = (float*)d_out;

    // ws: VTh fp16 (16 MB) | logcTh fp16 (4 MB) | ecnt | scnt | elist u16 | slist u16
    __half2* VTh     = (__half2*)d_ws;
    __half2* logcTh2 = (__half2*)((char*)d_ws + (size_t)Rr * Bsz * sizeof(__half));
    int*    ecnt     = (int*)((char*)logcTh2 + (size_t)Mm * Bsz * sizeof(__half));
    int*    scnt     = ecnt + Rr;
    ushort_t* elist  = (ushort_t*)(scnt + Mm);
    ushort_t* slist  = elist + Rr * EMAX;
    const size_t need = (size_t)Rr * Bsz * sizeof(__half)
                      + (size_t)Mm * Bsz * sizeof(__half)
                      + (size_t)(Rr + Mm) * sizeof(int)
                      + (size_t)(Rr * EMAX + Mm * SMAX) * sizeof(ushort_t);
    if (ws_size < need) return;

    zero_fill<<<296, 256, 0, stream>>>((unsigned*)slist, ecnt, scnt);
    prep_kernel<<<2560, 256, 0, stream>>>(conc, E, S, logcTh2, ecnt, elist, scnt, slist);
    rates_kernel<<<2048, 256, 0, stream>>>(logcTh2, kvec, ecnt, elist, VTh);
    assemble_kernel<<<1024, 256, 0, stream>>>(VTh, scnt, slist, out);
}

// Round 5
// 174.578 us; speedup vs baseline: 1.0712x; 1.0712x over previous
//
#include <hip/hip_runtime.h>
#include <hip/hip_fp16.h>

#define Bsz 1024
#define Mm  2048
#define Rr  8192
#define EMAX 32   // ushort slots per E column (col nnz mean ~4.1)
#define SMAX 64   // ushort slots per S row    (row nnz mean ~16.4)

typedef unsigned short ushort_t;

// ---- pass 0: zero ecnt only (32 KB). ----
__global__ __launch_bounds__(256) void zero_ecnt(int* __restrict__ p) {
    p[blockIdx.x * 256 + threadIdx.x] = 0;       // grid 32 -> 8192
}

// ---- pass 1: blocks 0..511 transpose+log; 512..2559 row-style E-scan.
// R1-R4 falsified load-engine/MLP/topology theories for the scan (all ~55us);
// scan rate ~2.3 TB/s is the workload's mixed L3/HBM service rate. So: stop
// tuning the scan; halve its bytes here (E only) and move the S-scan into the
// rates dispatch where it overlaps latency-bound gather work.
__global__ __launch_bounds__(256) void prep_kernel(
    const float* __restrict__ conc, const int* __restrict__ E,
    __half2* __restrict__ logcTh2, int* __restrict__ ecnt, ushort_t* __restrict__ elist)
{
    __shared__ int smem[64 * 65 + 1];            // transpose tile / escan buf+ctr
    const int bid = blockIdx.x;
    const int t   = threadIdx.x;

    if (bid < 512) {                             // ---- transpose + log -> fp16 ----
        float (*tile)[65] = (float(*)[65])smem;
        const int mt = (bid & 31) * 64;          // Mm/64 = 32
        const int bt = (bid >> 5) * 64;
        const int lm = t & 63;
        const int w  = t >> 6;
        for (int i = w; i < 64; i += 4)
            tile[lm][i] = __logf(conc[(size_t)(bt + i) * Mm + mt + lm]);
        __syncthreads();
        const int s       = bt >> 7;             // b-slice (128 b)
        const int colbase = (bt & 127) >> 1;
        __half2* dst = logcTh2 + (size_t)s * (Mm * 64);
        for (int idx = t; idx < 64 * 32; idx += 256) {
            const int j = idx >> 5, bp = idx & 31;
            dst[(mt + j) * 64 + colbase + bp] =
                __floats2half2_rn(tile[j][2 * bp], tile[j][2 * bp + 1]);
        }
    } else {                                     // ---- E-scan: owns row m ----
        const int m = bid - 512;
        int* buf = smem;
        int* nh  = smem + 256;
        if (t == 0) *nh = 0;
        __syncthreads();
        const int4* E4 = (const int4*)E + (size_t)m * 2048;
        int4 ev[8];
        #pragma unroll
        for (int u = 0; u < 8; ++u) ev[u] = E4[t + 256 * u];
        #pragma unroll
        for (int u = 0; u < 8; ++u) {
            const int r0 = (t + 256 * u) << 2;
            int v[4] = {ev[u].x, ev[u].y, ev[u].z, ev[u].w};
            #pragma unroll
            for (int q = 0; q < 4; ++q)
                if (v[q]) {
                    int i = atomicAdd(nh, 1);               // LDS atomic
                    if (i < 256) buf[i] = (v[q] << 13) | (r0 + q);
                }
        }
        __syncthreads();
        const int en = min(*nh, 256);
        if (t < en) {
            int wv = buf[t];
            int r  = wv & 0x1FFF;
            int e  = wv >> 13;
            int slot = atomicAdd(&ecnt[r], 1);              // ~16 atomics/block
            if (slot < EMAX) elist[r * EMAX + slot] = (ushort_t)((e << 11) | m);
        }
    }
}

// ---- pass 2 (fused): alternating groups of 8 blocks: S-scan | rates.
// S-scan (2048 blocks) feeds only assemble -> overlaps rates' latency wall.
// Group-of-8 interleave keeps rates' s == blockIdx&7 XCD/L2 pin intact and
// co-schedules both roles across the dispatch sequence.
__global__ __launch_bounds__(256) void rs_kernel(
    const __half2* __restrict__ logcTh2, const float* __restrict__ kvec,
    const int* __restrict__ ecnt, const ushort_t* __restrict__ elist,
    const int* __restrict__ S, int* __restrict__ scnt, ushort_t* __restrict__ slist,
    __half2* __restrict__ VTh)
{
    __shared__ int smem[257];                    // S-scan buf+ctr (1 KB)
    const int bid   = blockIdx.x;
    const int t     = threadIdx.x;
    const int grp   = bid >> 3;
    const int lane8 = bid & 7;

    if ((grp & 1) == 0) {                        // ---- S-scan: owns row m ----
        const int m = (grp >> 1) * 8 + lane8;    // even grps -> m in [0,2048)
        int* buf = smem;
        int* nh  = smem + 256;
        if (t == 0) *nh = 0;
        __syncthreads();
        const int4* S4 = (const int4*)S + (size_t)m * 2048;
        int4 sv[8];
        #pragma unroll
        for (int u = 0; u < 8; ++u) sv[u] = S4[t + 256 * u];
        #pragma unroll
        for (int u = 0; u < 8; ++u) {
            const int r0 = (t + 256 * u) << 2;
            int v[4] = {sv[u].x, sv[u].y, sv[u].z, sv[u].w};
            #pragma unroll
            for (int q = 0; q < 4; ++q)
                if (v[q]) {
                    int i = atomicAdd(nh, 1);               // LDS atomic
                    if (i < 256) buf[i] = ((v[q] + 2) << 13) | (r0 + q);
                }
        }
        __syncthreads();
        const int sn = min(*nh, SMAX);
        if (t == 0) scnt[m] = sn;
        if (t < SMAX)                            // write ALL slots: pads are safe
            slist[m * SMAX + t] = (t < sn) ? (ushort_t)buf[t]
                                           : (ushort_t)0x4000;   // enc 2 -> s=0
        return;
    }
    // ---- rates: VTh[s][r][64] = k[r]*exp(sum e*logcTh[s][m][64]) ----
    const int s   = lane8;                       // == blockIdx&7: XCD pin
    const int rch = grp >> 1;                    // odd grps -> 0..255, 32 r each
    const int col = t & 63;
    const int wr  = __builtin_amdgcn_readfirstlane(t >> 6);
    const __half2* lc = logcTh2 + (size_t)s * (Mm * 64);
    __half2* vt = VTh + (size_t)s * (Rr * 64);
    const int rb = rch * 32 + wr * 8;

    int  cnt[8]; int2 L0[8]; float kk[8];        // batch phase: independent s_loads
    #pragma unroll
    for (int i = 0; i < 8; ++i) {
        const int r = rb + i;
        cnt[i] = min(ecnt[r], EMAX);             // clamp: atomic counts can exceed slots
        L0[i]  = *(const int2*)(elist + (r << 5));
        kk[i]  = kvec[r];
    }
    float2 acc[8];
    unsigned w; float2 g; float v0, v1;
    #define EG2(word, c0, c1, A)                                               \
        w = (unsigned)(word);                                                  \
        v0 = (c0) ? (float)((w & 0xFFFF) >> 11) : 0.f;                         \
        v1 = (c1) ? (float)(w >> 27) : 0.f;                                    \
        g = __half22float2(lc[(w & 0x7FF) * 64 + col]);                        \
        A.x += v0 * g.x;  A.y += v0 * g.y;                                     \
        g = __half22float2(lc[((w >> 16) & 0x7FF) * 64 + col]);                \
        A.x += v1 * g.x;  A.y += v1 * g.y;
    #pragma unroll
    for (int i = 0; i < 8; ++i) {                // 32 gathers, one dependency level
        acc[i] = make_float2(0.f, 0.f);
        EG2(L0[i].x, cnt[i] > 0, cnt[i] > 1, acc[i])
        EG2(L0[i].y, cnt[i] > 2, cnt[i] > 3, acc[i])
    }
    #pragma unroll
    for (int i = 0; i < 8; ++i) {                // rare wave-uniform tails
        for (int j = 4; j < cnt[i]; j += 4) {
            int2 T = *(const int2*)(elist + ((rb + i) << 5) + j);
            EG2(T.x, j + 0 < cnt[i], j + 1 < cnt[i], acc[i])
            EG2(T.y, j + 2 < cnt[i], j + 3 < cnt[i], acc[i])
        }
    }
    #undef EG2
    #pragma unroll
    for (int i = 0; i < 8; ++i)
        vt[(rb + i) * 64 + col] =
            __floats2half2_rn(kk[i] * __expf(acc[i].x), kk[i] * __expf(acc[i].y));
}

// ---- pass 3: out[b][m] = sum s*VTh[s][r][64]; batched lists; LDS transpose stores ----
__global__ __launch_bounds__(256) void assemble_kernel(
    const __half2* __restrict__ VTh, const int* __restrict__ scnt,
    const ushort_t* __restrict__ slist, float* __restrict__ out)
{
    __shared__ float tile[128][17];              // [b-local][m-local] 8.5 KB
    const int s   = blockIdx.x & 7;              // same XCD pin as rates
    const int mch = blockIdx.x >> 3;             // 0..127, 16 m each
    const int col = threadIdx.x & 63;
    const int wm  = __builtin_amdgcn_readfirstlane(threadIdx.x >> 6);
    const __half2* vt = VTh + (size_t)s * (Rr * 64);
    const int m0 = mch * 16;

    int scn[4]; int4 W0[4], W1[4];               // batch phase: independent s_loads
    #pragma unroll
    for (int i = 0; i < 4; ++i) {
        const int m = m0 + i * 4 + wm;
        scn[i] = min(scnt[m], SMAX);
        W0[i]  = *(const int4*)(slist + (m << 6));
        W1[i]  = *(const int4*)(slist + (m << 6) + 8);
    }
    unsigned w; float2 v; float sw;
    #define SG(word, A)                                                        \
        w = (unsigned)(word);                                                  \
        v = __half22float2(vt[(w & 0x1FFF) * 64 + col]);                       \
        sw = (float)((int)((w & 0xFFFF) >> 13) - 2);                           \
        A.x += sw * v.x;  A.y += sw * v.y;                                     \
        v = __half22float2(vt[((w >> 16) & 0x1FFF) * 64 + col]);               \
        sw = (float)((int)(w >> 29) - 2);                                      \
        A.x += sw * v.x;  A.y += sw * v.y;
    #pragma unroll
    for (int i = 0; i < 4; ++i) {
        const int ml = i * 4 + wm;
        float2 a = make_float2(0.f, 0.f);
        SG(W0[i].x, a) SG(W0[i].y, a) SG(W0[i].z, a) SG(W0[i].w, a)
        SG(W1[i].x, a) SG(W1[i].y, a) SG(W1[i].z, a) SG(W1[i].w, a)
        for (int j = 16; j < scn[i]; j += 8) {   // pads materialized -> safe groups
            int4 T = *(const int4*)(slist + ((m0 + ml) << 6) + j);
            SG(T.x, a) SG(T.y, a) SG(T.z, a) SG(T.w, a)
        }
        tile[2 * col][ml]     = a.x;
        tile[2 * col + 1][ml] = a.y;
    }
    #undef SG
    __syncthreads();
    #pragma unroll
    for (int pass = 0; pass < 2; ++pass) {
        const int bl = (threadIdx.x >> 2) + pass * 64;
        const int fl = threadIdx.x & 3;
        float4 vv = *(const float4*)&tile[bl][fl * 4];
        *(float4*)(out + (size_t)(s * 128 + bl) * Mm + m0 + fl * 4) = vv;
    }
}

extern "C" void kernel_launch(void* const* d_in, const int* in_sizes, int n_in,
                              void* d_out, int out_size, void* d_ws, size_t ws_size,
                              hipStream_t stream) {
    const float* conc = (const float*)d_in[0];
    const int*   E    = (const int*)d_in[1];
    const int*   S    = (const int*)d_in[2];
    const float* kvec = (const float*)d_in[3];
    float* out = (float*)d_out;

    // ws: VTh fp16 (16 MB) | logcTh fp16 (4 MB) | ecnt | scnt | elist u16 | slist u16
    __half2* VTh     = (__half2*)d_ws;
    __half2* logcTh2 = (__half2*)((char*)d_ws + (size_t)Rr * Bsz * sizeof(__half));
    int*    ecnt     = (int*)((char*)logcTh2 + (size_t)Mm * Bsz * sizeof(__half));
    int*    scnt     = ecnt + Rr;
    ushort_t* elist  = (ushort_t*)(scnt + Mm);
    ushort_t* slist  = elist + Rr * EMAX;
    const size_t need = (size_t)Rr * Bsz * sizeof(__half)
                      + (size_t)Mm * Bsz * sizeof(__half)
                      + (size_t)(Rr + Mm) * sizeof(int)
                      + (size_t)(Rr * EMAX + Mm * SMAX) * sizeof(ushort_t);
    if (ws_size < need) return;

    zero_ecnt<<<32, 256, 0, stream>>>(ecnt);
    prep_kernel<<<2560, 256, 0, stream>>>(conc, E, logcTh2, ecnt, elist);
    rs_kernel<<<4096, 256, 0, stream>>>(logcTh2, kvec, ecnt, elist, S, scnt, slist, VTh);
    assemble_kernel<<<1024, 256, 0, stream>>>(VTh, scnt, slist, out);
}